// Round 14
// baseline (85.849 us; speedup 1.0000x reference)
//
#include <hip/hip_runtime.h>
#include <hip/hip_bf16.h>

typedef __bf16 bf16x8 __attribute__((ext_vector_type(8)));
typedef float  f32x4  __attribute__((ext_vector_type(4)));

// ---------------------------------------------------------------------------
// Stage 1: qkv = kern_tok @ qkv_w + qkv_b ; split into q(scaled),k,v
// ---------------------------------------------------------------------------
__global__ __launch_bounds__(192) void qkv_kernel(
    const float* __restrict__ conv_w, const float* __restrict__ qkv_w,
    const float* __restrict__ qkv_b,
    float* __restrict__ qv, float* __restrict__ kvv, float* __restrict__ vv)
{
    __shared__ float tok[64];
    const int bid = blockIdx.x;          // co*36 + s
    const int co = bid / 36, s = bid - co * 36;
    const int w = s / 9, p = s - w * 9;
    const int t = threadIdx.x;           // 192
    if (t < 64) tok[t] = conv_w[(((w * 64 + co) * 64 + t) * 9) + p];
    __syncthreads();
    float acc = qkv_b[t];
#pragma unroll 8
    for (int ci = 0; ci < 64; ++ci) acc += tok[ci] * qkv_w[ci * 192 + t];
    const int trip = t >> 6, rem = t & 63, h = rem >> 3, d = rem & 7;
    if (trip == 0) acc *= 0.35355339059327373f;   // hd^-0.5, hd=8
    float* dst = (trip == 0) ? qv : ((trip == 1) ? kvv : vv);
    dst[((co * 8 + h) * 36 + s) * 8 + d] = acc;
}

// ---------------------------------------------------------------------------
// Stage 2: attention per (co, head): softmax(q k^T) v  -> ao[co][s][h*8+d]
// ---------------------------------------------------------------------------
__global__ __launch_bounds__(64) void attn_kernel(
    const float* __restrict__ qv, const float* __restrict__ kvv,
    const float* __restrict__ vv, float* __restrict__ ao)
{
    __shared__ float kl[288], vl[288];
    const int bid = blockIdx.x;          // co*8 + h
    const int t = threadIdx.x;           // 64
    const float* kb = kvv + bid * 288;
    const float* vb = vv + bid * 288;
    for (int i = t; i < 288; i += 64) { kl[i] = kb[i]; vl[i] = vb[i]; }
    __syncthreads();
    if (t < 36) {
        float q[8];
        const float* qb = qv + bid * 288 + t * 8;
#pragma unroll
        for (int d = 0; d < 8; ++d) q[d] = qb[d];
        float sc[36];
        float mx = -1e30f;
#pragma unroll
        for (int u = 0; u < 36; ++u) {
            float a = 0.f;
#pragma unroll
            for (int d = 0; d < 8; ++d) a += q[d] * kl[u * 8 + d];
            sc[u] = a;
            mx = fmaxf(mx, a);
        }
        float sum = 0.f;
        float o[8] = {0.f,0.f,0.f,0.f,0.f,0.f,0.f,0.f};
#pragma unroll
        for (int u = 0; u < 36; ++u) {
            float e = expf(sc[u] - mx);
            sum += e;
#pragma unroll
            for (int d = 0; d < 8; ++d) o[d] += e * vl[u * 8 + d];
        }
        const float inv = 1.0f / sum;
        const int co = bid >> 3, h = bid & 7;
        float* dst = ao + (co * 36 + t) * 64 + h * 8;
#pragma unroll
        for (int d = 0; d < 8; ++d) dst[d] = o[d] * inv;
    }
}

// ---------------------------------------------------------------------------
// Stage 3: proj + SE + write bf16 kernels.
// kout layout: [((h*4 + w)*9 + p)][co][ci32]  (4 KB chunks = one
// (tap, ci-half); conv stages exactly one chunk per pipeline stage).
// ---------------------------------------------------------------------------
__global__ __launch_bounds__(64) void proj_se_kernel(
    const float* __restrict__ ao, const float* __restrict__ proj_w,
    const float* __restrict__ proj_b,
    const float* __restrict__ se_w1, const float* __restrict__ se_b1,
    const float* __restrict__ se_w2, const float* __restrict__ se_b2,
    ushort* __restrict__ kout)
{
    __shared__ float al[9][64];
    __shared__ float pool[64];
    __shared__ float hb[4];
    const int bid = blockIdx.x;          // w*64 + co
    const int w = bid >> 6, co = bid & 63;
    const int t = threadIdx.x;           // 64 (= ci)
    for (int i = t; i < 576; i += 64) {
        int p = i >> 6, j = i & 63;
        al[p][j] = ao[(co * 36 + w * 9 + p) * 64 + j];
    }
    __syncthreads();
    float kv[9];
#pragma unroll
    for (int p = 0; p < 9; ++p) {
        float a = proj_b[t];
#pragma unroll 8
        for (int j = 0; j < 64; ++j) a += al[p][j] * proj_w[j * 64 + t];
        kv[p] = a;
    }
    float pl = 0.f;
#pragma unroll
    for (int p = 0; p < 9; ++p) pl += kv[p];
    pool[t] = pl * (1.0f / 9.0f);
    __syncthreads();
    if (t < 4) {
        float hh = se_b1[w * 4 + t];
#pragma unroll 8
        for (int c = 0; c < 64; ++c) hh += pool[c] * se_w1[(w * 4 + t) * 64 + c];
        hb[t] = fmaxf(hh, 0.0f);
    }
    __syncthreads();
    float z = se_b2[w * 64 + t];
#pragma unroll
    for (int d = 0; d < 4; ++d) z += hb[d] * se_w2[(w * 64 + t) * 4 + d];
    const float sg = 1.0f / (1.0f + expf(-z));
    const int hhalf = t >> 5, ci32 = t & 31;
#pragma unroll
    for (int p = 0; p < 9; ++p) {
        __hip_bfloat16 hv = __float2bfloat16(kv[p] * sg);
        kout[(((hhalf * 4 + w) * 9) + p) * 2048 + co * 32 + ci32] = *(const ushort*)&hv;
    }
}

// ---------------------------------------------------------------------------
// Stage 4: dynamic per-window 3x3 conv, implicit GEMM, bf16 MFMA.
//
// Round-14 = R13's verified pipeline with a 16x8 px tile (was 16x16).
// Motivation: the (256,4) spill wall came from acc[4][4]=64 AGPR. Halving
// the per-wave output (wave = 4 rows x 8 j = 2 M-tiles of 2rows x 8j)
// gives acc[2][4]=32 -> (256,4) fits with ~40 regs headroom:
//   - LDS: in_lds 18x10x64 bf16 = 23040 B + kern 3x4 KB = 35328 B
//     -> 4 blocks/CU (141312 <= 163840) = 16 waves/CU (+33% vs R13's 12).
//   - Per-CU-stage LDS reads unchanged: 16 waves x (2 Af + 4 Kf) = 96 b128
//     (R13: 12 x 8 = 96) -- the LDS pipe does not worsen.
//   - M-tile = 2 rows x 8 j: lane l15 -> px (l15>>3, l15&7). The MFMA
//     D-layout permutes identically, so the verified LDS-transpose
//     epilogue carries over with px -> (i=px>>3, j=px&7).
//   - All R13-verified machinery unchanged: kern triple-buffer counted
//     vmcnt(1) (vmcnt(0) at s=17), issue s+2 right after barrier, linear
//     gll dest + pre-swizzled global source, 0-conflict input swizzle,
//     plain cached 1 KB-contiguous epilogue stores.
// Grid 4096 blocks (8 i-tiles x 16 j-tiles x 32 images), 4096%8==0 for
// the bijective XCD remap.
// Kill-switch: WRITE_SIZE must stay ~131072 KB (>150 MB => spill => the
// (256,4) path is dead even at acc=32; revert to R13, declare plateau).
// ---------------------------------------------------------------------------
__global__ __launch_bounds__(256, 4) void conv_kernel(
    const float* __restrict__ x, const ushort* __restrict__ kern,
    float* __restrict__ out)
{
    __shared__ alignas(16) ushort in_lds[18 * 10 * 64];   // 23040 B
    __shared__ alignas(16) ushort kn_lds[3 * 2048];       // 12288 B (3 x 4KB)

    const int tid = threadIdx.x;

    // ---- XCD-chunked bijective remap: XCD k gets nb in [k*512,(k+1)*512)
    const int bid = blockIdx.x;                 // 0..4095, xcd = bid & 7
    const int nb  = ((bid & 7) << 9) + (bid >> 3);
    const int bz  = nb >> 7;                    // (w*8+b), 128 tiles/image
    const int rem = nb & 127;
    const int i0  = (rem >> 4) << 4;            // 8 i-tiles of 16 rows
    const int j0  = (rem & 15) << 3;            // 16 j-tiles of 8 cols
    const int w = bz >> 3, b = bz & 7;
    const int gi = w >> 1, gj = w & 1;

    const int wv   = tid >> 6;
    const int lane = tid & 63;
    const int l15  = lane & 15;
    const int hi4  = lane >> 4;        // 0..3

    // ---- async kern stage: stage s = (p = s>>1, half = s&1) -> one 4 KB
    // chunk at kern + (((half*4+w)*9)+p)*4096. Linear LDS dest; read-side
    // swizzle realized by pre-swizzling the GLOBAL source (both-sides rule).
    const char* kern_b = (const char*)kern;
    const int ksrc = (lane << 4) ^ (((lane >> 3) & 3) << 4);
    auto stage_kern = [&](int s, int buf) {
        const int p = s >> 1, hh = s & 1;
        const char* gs = kern_b + ((size_t)((((hh * 4 + w) * 9)) + p) << 12);
        __builtin_amdgcn_global_load_lds(
            (const __attribute__((address_space(1))) unsigned int*)(gs + (wv << 10) + ksrc),
            (__attribute__((address_space(3))) unsigned int*)
                ((char*)kn_lds + (buf << 12) + (wv << 10)),
            16, 0, 0);
    };

    // ---- prologue: kern stages 0,1 fly under the input staging burst
    stage_kern(0, 0);
    stage_kern(1, 1);

    // input staging: 18x10 px halo tile, 64 ch, fp32->bf16, 16 thr/px.
    // 12 clamped unconditional loads, all issued before the cvt/write pass.
    // LDS position: (pp<<7) + ((cc*2) ^ ((q&7)<<4))  [0-conflict swizzle]
    {
        const int cc = (tid & 15) << 2;    // channel 0..60
        const int p0 = tid >> 4;           // 0..15
        float4 v[12];
        unsigned okm = 0;
#pragma unroll
        for (int k = 0; k < 12; ++k) {
            const int pp = p0 + (k << 4);          // <= 191
            const int ppc = pp < 179 ? pp : 179;
            const int r = ppc / 10, q = ppc - r * 10;
            const int iy = i0 - 1 + r, jx = j0 - 1 + q;
            const bool ok = (pp < 180) & (iy >= 0) & (iy < 128) & (jx >= 0) & (jx < 128);
            const int iyc = iy < 0 ? 0 : (iy > 127 ? 127 : iy);
            const int jxc = jx < 0 ? 0 : (jx > 127 ? 127 : jx);
            const size_t xi = (((size_t)b << 16) +
                               (size_t)(gi * 128 + iyc) * 256 + (size_t)(gj * 128 + jxc)) * 64 + cc;
            v[k] = *(const float4*)(x + xi);
            okm |= (unsigned)ok << k;
        }
#pragma unroll
        for (int k = 0; k < 12; ++k) {
            const int pp = p0 + (k << 4);
            if (pp < 180) {
                const int r = pp / 10, q = pp - r * 10;
                float4 z = (okm >> k) & 1 ? v[k] : make_float4(0.f, 0.f, 0.f, 0.f);
                union { ushort4 u; ushort h4[4]; } tmp;
                __hip_bfloat16 b0 = __float2bfloat16(z.x); tmp.h4[0] = *(const ushort*)&b0;
                __hip_bfloat16 b1 = __float2bfloat16(z.y); tmp.h4[1] = *(const ushort*)&b1;
                __hip_bfloat16 b2 = __float2bfloat16(z.z); tmp.h4[2] = *(const ushort*)&b2;
                __hip_bfloat16 b3 = __float2bfloat16(z.w); tmp.h4[3] = *(const ushort*)&b3;
                *(ushort4*)((char*)in_lds +
                    ((pp << 7) + ((cc << 1) ^ ((q & 7) << 4)))) = tmp.u;
            }
        }
    }

    f32x4 acc[2][4];
#pragma unroll
    for (int mf = 0; mf < 2; ++mf)
#pragma unroll
        for (int nf = 0; nf < 4; ++nf)
            acc[mf][nf] = (f32x4){0.f, 0.f, 0.f, 0.f};

    __syncthreads();     // the ONE full drain: input ds_writes + kern 0,1

    const int row_half = l15 >> 3;     // lane's row within the 2-row M-tile
    const int jl       = l15 & 7;      // lane's j within the tile

#pragma unroll
    for (int s = 0; s < 18; ++s) {
        // counted wait: set s retired when <=1 outstanding ({s, s+1} in
        // flight at stage top). s=17: queue is {17} alone -> vmcnt(0).
        if (s < 17) asm volatile("s_waitcnt vmcnt(1)" ::: "memory");
        else        asm volatile("s_waitcnt vmcnt(0)" ::: "memory");
        __builtin_amdgcn_sched_barrier(0);
        __builtin_amdgcn_s_barrier();      // all waves' set-s loads in LDS
        __builtin_amdgcn_sched_barrier(0);

        // issue load(s+2) into buf[(s+2)%3] before compute (R13-verified)
        if (s < 16) stage_kern(s + 2, (s + 2) % 3);

        const int buf = s % 3;
        const int p = s >> 1, hh = s & 1;
        const int kh = p / 3, kw = p - kh * 3;

        // kern fragments: co = nf*16+l15, ci-chunk hi4 within this half
        bf16x8 Kf[4];
#pragma unroll
        for (int nf = 0; nf < 4; ++nf) {
            const int co = nf * 16 + l15;
            Kf[nf] = *(const bf16x8*)((const char*)kn_lds +
                      ((buf << 12) + (co << 6) +
                       ((hi4 << 4) ^ (((co >> 1) & 3) << 4))));
        }

        const int q = jl + kw;             // 0..9
        const int swz = (q & 7) << 4;
        const int c2 = (hh << 6) | (hi4 << 4);
#pragma unroll
        for (int mf = 0; mf < 2; ++mf) {
            const int r = wv * 4 + mf * 2 + row_half + kh;   // 0..17
            bf16x8 Af = *(const bf16x8*)((const char*)in_lds +
                          (((r * 10 + q) << 7) + (c2 ^ swz)));
#pragma unroll
            for (int nf = 0; nf < 4; ++nf)
                acc[mf][nf] = __builtin_amdgcn_mfma_f32_16x16x32_bf16(
                    Kf[nf], Af, acc[mf][nf], 0, 0, 0);
        }
    }

    // ---- pre-epilogue barrier: my ds_reads retired, then all waves arrive
    // => nobody still reads in_lds when we overwrite it.
    asm volatile("s_waitcnt lgkmcnt(0)" ::: "memory");
    __builtin_amdgcn_sched_barrier(0);
    __builtin_amdgcn_s_barrier();
    __builtin_amdgcn_sched_barrier(0);

    // ---- LDS-transpose epilogue (wave-private 4 KB region; 16 KB total
    // <= 23040 B in_lds). px index within mf-tile: (i = px>>3, j = px&7).
    // Plain cached stores, 1 KB contiguous per wave-instruction.
    char* ep = (char*)in_lds + (wv << 12);
#pragma unroll
    for (int mf = 0; mf < 2; ++mf) {
        const size_t rowbase = ((size_t)b << 16) +
                               (size_t)(gi * 128 + i0 + wv * 4 + mf * 2) * 256 +
                               (size_t)(gj * 128 + j0);
        // scatter: lane(l15,hi4) holds co = nf*16+hi4*4+reg at px l15
#pragma unroll
        for (int nf = 0; nf < 4; ++nf) {
            const int off = (nf * 64 + hi4 * 16) ^ ((l15 & 7) << 4);
            *(f32x4*)(ep + l15 * 256 + off) = acc[mf][nf];
        }
        // gather: lane(l15,hi4) reads co-chunk l15 of px t*4+hi4
#pragma unroll
        for (int t = 0; t < 4; ++t) {
            const int px = t * 4 + hi4;
            f32x4 vv4 = *(const f32x4*)(ep + px * 256 + ((l15 << 4) ^ ((px & 7) << 4)));
            *(f32x4*)(out + (rowbase + (px >> 3) * 256 + (px & 7)) * 64 + l15 * 4) = vv4;
        }
    }
}

// ---------------------------------------------------------------------------
extern "C" void kernel_launch(void* const* d_in, const int* in_sizes, int n_in,
                              void* d_out, int out_size, void* d_ws, size_t ws_size,
                              hipStream_t stream)
{
    const float* x      = (const float*)d_in[0];
    const float* conv_w = (const float*)d_in[1];
    const float* qkv_w  = (const float*)d_in[2];
    const float* qkv_b  = (const float*)d_in[3];
    const float* proj_w = (const float*)d_in[4];
    const float* proj_b = (const float*)d_in[5];
    const float* se_w1  = (const float*)d_in[6];
    const float* se_b1  = (const float*)d_in[7];
    const float* se_w2  = (const float*)d_in[8];
    const float* se_b2  = (const float*)d_in[9];
    float* out = (float*)d_out;

    float* qv = (float*)d_ws;            // 147456 f
    float* kv = qv + 147456;             // 147456 f
    float* vv = kv + 147456;             // 147456 f
    float* ao = vv + 147456;             // 147456 f
    ushort* kb = (ushort*)(ao + 147456); // 147456 u16  (total ~2.6 MB)

    hipLaunchKernelGGL(qkv_kernel, dim3(2304), dim3(192), 0, stream,
                       conv_w, qkv_w, qkv_b, qv, kv, vv);
    hipLaunchKernelGGL(attn_kernel, dim3(512), dim3(64), 0, stream, qv, kv, vv, ao);
    hipLaunchKernelGGL(proj_se_kernel, dim3(256), dim3(64), 0, stream,
                       ao, proj_w, proj_b, se_w1, se_b1, se_w2, se_b2, kb);
    hipLaunchKernelGGL(conv_kernel, dim3(4096), dim3(256), 0, stream, x, kb, out);
}